// Round 5
// baseline (66.842 us; speedup 1.0000x reference)
//
#include <hip/hip_runtime.h>
#include <hip/hip_bf16.h>

typedef __attribute__((ext_vector_type(8))) short short8;
typedef __attribute__((ext_vector_type(4))) float f32x4;

#define B_  8
#define T_  2048
#define C_  768
#define H_  64
#define M_  (B_ * T_)   // 16384 rows

static __device__ __forceinline__ unsigned short f2bf(float f) {
    __hip_bfloat16 h = __float2bfloat16(f);
    return *reinterpret_cast<unsigned short*>(&h);
}

static __device__ __forceinline__ short8 make_frag(const unsigned short* p0, const unsigned short* p1) {
    const ushort4 a = *reinterpret_cast<const ushort4*>(p0);
    const ushort4 b = *reinterpret_cast<const ushort4*>(p1);
    short8 r;
    r[0] = (short)a.x; r[1] = (short)a.y; r[2] = (short)a.z; r[3] = (short)a.w;
    r[4] = (short)b.x; r[5] = (short)b.y; r[6] = (short)b.z; r[7] = (short)b.w;
    return r;
}

// XOR swizzle for LDS tiles with 64-ushort (128 B) rows (attn kernels).
static __device__ __forceinline__ int swz(int row, int u) {
    return row * 64 + ((((u) >> 3) ^ (row & 7)) << 3) + (u & 7);
}

// ---------------------------------------------------------------------------
// Kernel 0: W -> Wt  (transpose + fp32->bf16).  Wt[192][768] bf16.
// ---------------------------------------------------------------------------
__global__ __launch_bounds__(256) void prep_w(
    const float* __restrict__ Wq, const float* __restrict__ Wk, const float* __restrict__ Wv,
    unsigned short* __restrict__ Wt) {

    const int t   = threadIdx.x;
    const int mat = blockIdx.x / 48;
    const int kb  = blockIdx.x % 48;
    const int h   = t & 63;
    const int k0  = (kb * 4 + (t >> 6)) * 4;

    const float* Ws = (mat == 0) ? Wq : (mat == 1) ? Wk : Wv;
    ushort4 o;
    o.x = f2bf(Ws[(size_t)(k0 + 0) * H_ + h]);
    o.y = f2bf(Ws[(size_t)(k0 + 1) * H_ + h]);
    o.z = f2bf(Ws[(size_t)(k0 + 2) * H_ + h]);
    o.w = f2bf(Ws[(size_t)(k0 + 3) * H_ + h]);
    *reinterpret_cast<ushort4*>(&Wt[(size_t)(mat * 64 + h) * C_ + k0]) = o;
}

// ---------------------------------------------------------------------------
// Kernel 1: fused QKV projection, v4: 32-row blocks (512 blocks = 2/CU).
// Block = 32 rows x 192 cols; wave w owns cols w*48..w*48+47, all 32 rows.
// Two K-phases of 384; x staged bf16 in LDS in fragment-order chunks with
// XOR placement; B-frags read from L2-resident Wt with prefetch-1.
// ---------------------------------------------------------------------------
__global__ __launch_bounds__(256) void proj_kernel(
    const float* __restrict__ x, const unsigned short* __restrict__ Wt,
    unsigned short* __restrict__ qkv) {

    __shared__ unsigned short Als[2 * 12 * 512];   // 24 KB: [rt][kk][chunk*8]

    const int tid = threadIdx.x;
    const int w   = tid >> 6;
    const int l   = tid & 63;
    const int lg  = l >> 4;
    const int lc  = l & 15;
    const int row0 = blockIdx.x * 32;

    const int sr   = tid >> 3;         // row 0..31
    const int so   = tid & 7;          // k-oct phase 0..7
    const int srt  = sr >> 4;          // 0..1
    const int sr15 = sr & 15;

    f32x4 acc[2][3];
#pragma unroll
    for (int rt = 0; rt < 2; ++rt)
#pragma unroll
        for (int ct = 0; ct < 3; ++ct) acc[rt][ct] = (f32x4)0.f;

    const unsigned short* bbase[3];
#pragma unroll
    for (int ct = 0; ct < 3; ++ct)
        bbase[ct] = Wt + (size_t)(w * 48 + ct * 16 + lc) * C_ + lg * 8;

    for (int phase = 0; phase < 2; ++phase) {
        if (phase) __syncthreads();
        // ---- stage 32 rows x 384 k of x: 6 octs of 8 floats per thread
        float4 fa[6][2];
#pragma unroll
        for (int g = 0; g < 6; ++g) {
            const float* xp = x + (size_t)(row0 + sr) * C_ + phase * 384 + (so + 8 * g) * 8;
            fa[g][0] = *reinterpret_cast<const float4*>(xp);
            fa[g][1] = *reinterpret_cast<const float4*>(xp + 4);
        }
#pragma unroll
        for (int g = 0; g < 6; ++g) {
            const int j8  = so + 8 * g;
            const int kk  = j8 >> 2;
            const int so4 = j8 & 3;
            short8 v;
            v[0] = (short)f2bf(fa[g][0].x); v[1] = (short)f2bf(fa[g][0].y);
            v[2] = (short)f2bf(fa[g][0].z); v[3] = (short)f2bf(fa[g][0].w);
            v[4] = (short)f2bf(fa[g][1].x); v[5] = (short)f2bf(fa[g][1].y);
            v[6] = (short)f2bf(fa[g][1].z); v[7] = (short)f2bf(fa[g][1].w);
            *reinterpret_cast<short8*>(
                &Als[(srt * 12 + kk) * 512 + (so4 * 16 + (sr15 ^ so4)) * 8]) = v;
        }
        __syncthreads();

        // ---- compute 12 k-steps, B prefetch-1
        short8 bcur[3], bnxt[3];
#pragma unroll
        for (int ct = 0; ct < 3; ++ct)
            bcur[ct] = *reinterpret_cast<const short8*>(bbase[ct] + phase * 384);

#pragma unroll
        for (int kk = 0; kk < 12; ++kk) {
            if (kk < 11) {
#pragma unroll
                for (int ct = 0; ct < 3; ++ct)
                    bnxt[ct] = *reinterpret_cast<const short8*>(bbase[ct] + phase * 384 + (kk + 1) * 32);
            }
            short8 af[2];
#pragma unroll
            for (int rt = 0; rt < 2; ++rt)
                af[rt] = *reinterpret_cast<const short8*>(
                    &Als[(rt * 12 + kk) * 512 + (lg * 16 + (lc ^ lg)) * 8]);
#pragma unroll
            for (int rt = 0; rt < 2; ++rt)
#pragma unroll
                for (int ct = 0; ct < 3; ++ct)
                    acc[rt][ct] = __builtin_amdgcn_mfma_f32_16x16x32_bf16(af[rt], bcur[ct], acc[rt][ct], 0, 0, 0);
            if (kk < 11) {
#pragma unroll
                for (int ct = 0; ct < 3; ++ct) bcur[ct] = bnxt[ct];
            }
        }
    }

    // ---- epilogue: C/D layout col=lc, row=lg*4+j
#pragma unroll
    for (int ct = 0; ct < 3; ++ct) {
        const int col = w * 48 + ct * 16 + lc;
        const int mat = col >> 6;
        const int h   = col & 63;
#pragma unroll
        for (int rt = 0; rt < 2; ++rt)
#pragma unroll
            for (int j = 0; j < 4; ++j) {
                const int grow = row0 + rt * 16 + lg * 4 + j;
                qkv[(size_t)mat * (M_ * H_) + (size_t)grow * H_ + h] = f2bf(acc[rt][ct][j]);
            }
    }
}

// ---------------------------------------------------------------------------
// Segment bookkeeping for split-KV flash attention (KV tiles of 64 rows).
// ---------------------------------------------------------------------------
#define SEG_FLOATS 4224
#define LOG2E_SCALE 0.18033688011112042f   // 0.125 * log2(e)

template<int SEG>
static __device__ __forceinline__ int segs_per_batch() { return SEG == 32 ? 32 : 80; }

template<int SEG>
static __device__ __forceinline__ void decode_seg(int r, int& qt, int& seg) {
    if (SEG == 32) { qt = r; seg = 0; return; }
    if (r < 8)       { qt = r;                seg = 0; }
    else if (r < 24) { qt = 8  + (r - 8) / 2; seg = (r - 8) & 1; }
    else if (r < 48) { qt = 16 + (r - 24) / 3; seg = (r - 24) % 3; }
    else             { qt = 24 + (r - 48) / 4; seg = (r - 48) & 3; }
}

template<int SEG>
static __device__ __forceinline__ int seg_prefix(int qt) {
    if (SEG == 32) return qt;
    if (qt < 8)  return qt;
    if (qt < 16) return 8  + 2 * (qt - 8);
    if (qt < 24) return 24 + 3 * (qt - 16);
    return 48 + 4 * (qt - 24);
}

// ---------------------------------------------------------------------------
// Kernel 2a: partial causal flash attention, swapped-operand + reg-dbuf.
// Per tile: WRITE(LDS from regs of tile t) -> barrier -> LOAD(regs, t+1)
// -> compute(t).  Global-load latency for t+1 hides under compute of t.
// Softmax fully in-register; exact defer-rescale when max doesn't grow.
// ---------------------------------------------------------------------------
template<int SEG>
__global__ __launch_bounds__(256) void attn_partial(
    const unsigned short* __restrict__ qkv, float* __restrict__ part) {

    const int spb = segs_per_batch<SEG>();
    const int b   = blockIdx.x / spb;
    const int r_  = blockIdx.x % spb;
    int qt, seg;
    decode_seg<SEG>(r_, qt, seg);

    const int tid = threadIdx.x;
    const int w  = tid >> 6;
    const int l  = tid & 63;
    const int lg = l >> 4;
    const int lc = l & 15;

    __shared__ unsigned short Kl[64 * 64];   // K tile [s][h], swizzled
    __shared__ unsigned short Vt[64 * 64];   // V^T tile [h][s], swizzled

    const unsigned short* Qg = qkv;
    const unsigned short* Kg = qkv + (size_t)M_ * H_;
    const unsigned short* Vg = qkv + (size_t)2 * M_ * H_;

    // per-thread staging coordinates (constant across tiles)
    const int sK0 = tid >> 3;               // K row rep0 (rep1: +32)
    const int c16 = tid & 7;                // K 16B chunk
    const int kOff  = sK0 * H_ + c16 * 8;   // global offset within tile
    const int kLds0 = sK0 * 64 + ((c16 ^ (sK0 & 7)) << 3);
    const int kLds1 = (sK0 + 32) * 64 + ((c16 ^ ((sK0 + 32) & 7)) << 3);

    const int sV0 = 2 * (tid >> 4);         // V row pair rep0 (rep1: +32)
    const int h0  = (tid & 15) * 4;
    const int vOff = sV0 * H_ + h0;

    // Q fragment (B-operand: col = q = w*16+lc, k = h)
    const unsigned short* qrow = Qg + (size_t)(b * T_ + qt * 64 + w * 16 + lc) * H_;
    short8 qf[2];
#pragma unroll
    for (int ks = 0; ks < 2; ++ks)
        qf[ks] = make_frag(qrow + ks * 32 + lg * 4, qrow + ks * 32 + lg * 4 + 16);

    float mval = -1e30f, lsum = 0.f;   // per-lane state for q = w*16+lc
    f32x4 oT[4];                       // O^T: h = ht*16+4*lg+reg, q = lc
#pragma unroll
    for (int t = 0; t < 4; ++t) oT[t] = (f32x4)0.f;

    const int q_glob = qt * 64 + w * 16 + lc;

    const int kv_beg = seg * SEG;
    const int kv_end = min(kv_beg + SEG, qt + 1);

    // staged-tile registers (named; no runtime indexing)
    short8  kreg0, kreg1;
    ushort4 va0, vb0, va1, vb1;

    auto load_tiles = [&](int kv) {
        const size_t off = (size_t)(b * T_ + kv * 64) * H_;
        kreg0 = *reinterpret_cast<const short8*>(&Kg[off + kOff]);
        kreg1 = *reinterpret_cast<const short8*>(&Kg[off + kOff + 32 * H_]);
        va0 = *reinterpret_cast<const ushort4*>(&Vg[off + vOff]);
        vb0 = *reinterpret_cast<const ushort4*>(&Vg[off + vOff + H_]);
        va1 = *reinterpret_cast<const ushort4*>(&Vg[off + vOff + 32 * H_]);
        vb1 = *reinterpret_cast<const ushort4*>(&Vg[off + vOff + 32 * H_ + H_]);
    };

    load_tiles(kv_beg);

    for (int kv = kv_beg; kv < kv_end; ++kv) {
        __syncthreads();   // all waves done reading LDS of previous tile
        // ---- write staged regs to LDS (vmcnt wait folds in here)
        *reinterpret_cast<short8*>(&Kl[kLds0]) = kreg0;
        *reinterpret_cast<short8*>(&Kl[kLds1]) = kreg1;
#pragma unroll
        for (int j = 0; j < 4; ++j) {
            const unsigned int p0 = (unsigned int)(&va0.x)[j] | ((unsigned int)(&vb0.x)[j] << 16);
            *reinterpret_cast<unsigned int*>(&Vt[swz(h0 + j, sV0)]) = p0;
            const unsigned int p1 = (unsigned int)(&va1.x)[j] | ((unsigned int)(&vb1.x)[j] << 16);
            *reinterpret_cast<unsigned int*>(&Vt[swz(h0 + j, sV0 + 32)]) = p1;
        }
        __syncthreads();   // tile visible

        // ---- issue next tile's loads; latency hides under compute below
        if (kv + 1 < kv_end) load_tiles(kv + 1);

        // ---- S^T = (K Q^T): rows s = st*16 + 4*lg + reg, col q = lc
        f32x4 sT[4];
#pragma unroll
        for (int st = 0; st < 4; ++st) {
            f32x4 accs = (f32x4)0.f;
#pragma unroll
            for (int ks = 0; ks < 2; ++ks) {
                const short8 kf = make_frag(&Kl[swz(st * 16 + lc, ks * 32 + lg * 4)],
                                            &Kl[swz(st * 16 + lc, ks * 32 + lg * 4 + 16)]);
                accs = __builtin_amdgcn_mfma_f32_16x16x32_bf16(kf, qf[ks], accs, 0, 0, 0);
            }
            sT[st] = accs;
        }

        // ---- in-register online softmax (log2 domain)
        float p[4][4];
#pragma unroll
        for (int st = 0; st < 4; ++st)
#pragma unroll
            for (int r = 0; r < 4; ++r)
                p[st][r] = sT[st][r] * LOG2E_SCALE;

        if (kv == qt) {
#pragma unroll
            for (int st = 0; st < 4; ++st)
#pragma unroll
                for (int r = 0; r < 4; ++r)
                    if ((kv * 64 + st * 16 + lg * 4 + r) > q_glob) p[st][r] = -1e30f;
        }

        float pm[4];
#pragma unroll
        for (int st = 0; st < 4; ++st)
            pm[st] = fmaxf(fmaxf(p[st][0], p[st][1]), fmaxf(p[st][2], p[st][3]));
        float pmax = fmaxf(fmaxf(pm[0], pm[1]), fmaxf(pm[2], pm[3]));
        pmax = fmaxf(pmax, __shfl_xor(pmax, 16));
        pmax = fmaxf(pmax, __shfl_xor(pmax, 32));

        // exact defer-rescale: if no lane's max grew, alpha == 1 exactly
        if (!__all(pmax <= mval)) {
            const float mnew  = fmaxf(mval, pmax);
            const float alpha = exp2f(mval - mnew);
            mval = mnew;
            lsum *= alpha;
#pragma unroll
            for (int ht = 0; ht < 4; ++ht) oT[ht] *= alpha;
        }

        float ps[4];
#pragma unroll
        for (int st = 0; st < 4; ++st) {
#pragma unroll
            for (int r = 0; r < 4; ++r)
                p[st][r] = exp2f(p[st][r] - mval);
            ps[st] = (p[st][0] + p[st][1]) + (p[st][2] + p[st][3]);
        }
        float srow = (ps[0] + ps[1]) + (ps[2] + ps[3]);
        srow += __shfl_xor(srow, 16);
        srow += __shfl_xor(srow, 32);
        lsum += srow;

        // ---- pack P^T -> bf16 B-frags (layout identity: D row s == B-frag k)
        short8 pb[2];
#pragma unroll
        for (int ks = 0; ks < 2; ++ks) {
#pragma unroll
            for (int r = 0; r < 4; ++r) {
                pb[ks][r]     = (short)f2bf(p[2 * ks][r]);
                pb[ks][r + 4] = (short)f2bf(p[2 * ks + 1][r]);
            }
        }

        // ---- O^T += V^T P^T
#pragma unroll
        for (int ks = 0; ks < 2; ++ks) {
#pragma unroll
            for (int ht = 0; ht < 4; ++ht) {
                const short8 vf = make_frag(&Vt[swz(ht * 16 + lc, ks * 32 + lg * 4)],
                                            &Vt[swz(ht * 16 + lc, ks * 32 + lg * 4 + 16)]);
                oT[ht] = __builtin_amdgcn_mfma_f32_16x16x32_bf16(vf, pb[ks], oT[ht], 0, 0, 0);
            }
        }
    }

    // ---- write partial: O^T regs land as [q][h] float4 stores
    float* base = part + (size_t)blockIdx.x * SEG_FLOATS;
#pragma unroll
    for (int ht = 0; ht < 4; ++ht)
        *reinterpret_cast<f32x4*>(&base[(w * 16 + lc) * 64 + ht * 16 + lg * 4]) = oT[ht];
    if (lg == 0) {
        base[4096 + w * 16 + lc] = mval;
        base[4160 + w * 16 + lc] = lsum;
    }
}

// ---------------------------------------------------------------------------
// Kernel 2b: merge segments, normalize, write output.
// ---------------------------------------------------------------------------
template<int SEG>
__global__ __launch_bounds__(256) void attn_merge(
    const float* __restrict__ part, float* __restrict__ out) {

    const int b  = blockIdx.x >> 5;
    const int qt = blockIdx.x & 31;
    const int nseg = (SEG == 32) ? 1 : (qt / 8 + 1);
    const int spb  = segs_per_batch<SEG>();
    const float* base0 = part + (size_t)(b * spb + seg_prefix<SEG>(qt)) * SEG_FLOATS;

    const int tid = threadIdx.x;
    const int row = tid >> 2;
    const int c0  = (tid & 3) * 16;

    float M = -1e30f;
    for (int s = 0; s < nseg; ++s)
        M = fmaxf(M, base0[(size_t)s * SEG_FLOATS + 4096 + row]);

    float L = 0.f;
    f32x4 acc[4];
#pragma unroll
    for (int k = 0; k < 4; ++k) acc[k] = (f32x4)0.f;

    for (int s = 0; s < nseg; ++s) {
        const float* sb = base0 + (size_t)s * SEG_FLOATS;
        const float wsc = exp2f(sb[4096 + row] - M);
        L += sb[4160 + row] * wsc;
#pragma unroll
        for (int k = 0; k < 4; ++k) {
            const f32x4 ov = *reinterpret_cast<const f32x4*>(&sb[row * 64 + c0 + 4 * k]);
            acc[k] += ov * wsc;
        }
    }
    const float inv = 1.f / L;
    float* op = out + (size_t)(b * T_ + qt * 64 + row) * H_ + c0;
#pragma unroll
    for (int k = 0; k < 4; ++k)
        *reinterpret_cast<f32x4*>(&op[4 * k]) = acc[k] * inv;
}

// ---------------------------------------------------------------------------
// Fallback: single-pass attention (used only if ws too small for split-KV).
// ---------------------------------------------------------------------------
__global__ __launch_bounds__(256) void attn_kernel(
    const unsigned short* __restrict__ qkv, float* __restrict__ out) {

    const int b  = blockIdx.x >> 5;
    const int qt = blockIdx.x & 31;
    const int tid = threadIdx.x;
    const int w  = tid >> 6;
    const int l  = tid & 63;
    const int lg = l >> 4;
    const int lc = l & 15;

    __shared__ unsigned short Kl[64 * 64];
    __shared__ unsigned short Vt[64 * 64];

    const unsigned short* Qg = qkv;
    const unsigned short* Kg = qkv + (size_t)M_ * H_;
    const unsigned short* Vg = qkv + (size_t)2 * M_ * H_;

    const unsigned short* qrow = Qg + (size_t)(b * T_ + qt * 64 + w * 16 + lc) * H_;
    short8 qf[2];
#pragma unroll
    for (int ks = 0; ks < 2; ++ks)
        qf[ks] = make_frag(qrow + ks * 32 + lg * 4, qrow + ks * 32 + lg * 4 + 16);

    float mval = -1e30f, lsum = 0.f;
    f32x4 oT[4];
#pragma unroll
    for (int t = 0; t < 4; ++t) oT[t] = (f32x4)0.f;

    const int q_glob = qt * 64 + w * 16 + lc;

    for (int kv = 0; kv <= qt; ++kv) {
        __syncthreads();
#pragma unroll
        for (int rep = 0; rep < 2; ++rep) {
            const int idx = rep * 256 + tid;
            const int s   = idx >> 3;
            const int c16 = idx & 7;
            const size_t g = (size_t)(b * T_ + kv * 64 + s) * H_ + c16 * 8;
            short8 kvec = *reinterpret_cast<const short8*>(&Kg[g]);
            *reinterpret_cast<short8*>(&Kl[s * 64 + ((c16 ^ (s & 7)) << 3)]) = kvec;
        }
#pragma unroll
        for (int rep = 0; rep < 2; ++rep) {
            const int idx = rep * 256 + tid;
            const int s2  = idx >> 4;
            const int h0  = (idx & 15) * 4;
            const int s   = 2 * s2;
            const size_t g = (size_t)(b * T_ + kv * 64 + s) * H_ + h0;
            ushort4 v0 = *reinterpret_cast<const ushort4*>(&Vg[g]);
            ushort4 v1 = *reinterpret_cast<const ushort4*>(&Vg[g + H_]);
#pragma unroll
            for (int j = 0; j < 4; ++j) {
                const int h = h0 + j;
                unsigned int pk = (unsigned int)(&v0.x)[j] | ((unsigned int)(&v1.x)[j] << 16);
                *reinterpret_cast<unsigned int*>(&Vt[swz(h, s)]) = pk;
            }
        }
        __syncthreads();

        f32x4 sT[4];
#pragma unroll
        for (int st = 0; st < 4; ++st) {
            f32x4 accs = (f32x4)0.f;
#pragma unroll
            for (int ks = 0; ks < 2; ++ks) {
                const short8 kf = make_frag(&Kl[swz(st * 16 + lc, ks * 32 + lg * 4)],
                                            &Kl[swz(st * 16 + lc, ks * 32 + lg * 4 + 16)]);
                accs = __builtin_amdgcn_mfma_f32_16x16x32_bf16(kf, qf[ks], accs, 0, 0, 0);
            }
            sT[st] = accs;
        }

        float p[4][4];
#pragma unroll
        for (int st = 0; st < 4; ++st)
#pragma unroll
            for (int r = 0; r < 4; ++r)
                p[st][r] = sT[st][r] * LOG2E_SCALE;

        if (kv == qt) {
#pragma unroll
            for (int st = 0; st < 4; ++st)
#pragma unroll
                for (int r = 0; r < 4; ++r)
                    if ((kv * 64 + st * 16 + lg * 4 + r) > q_glob) p[st][r] = -1e30f;
        }

        float pm[4];
#pragma unroll
        for (int st = 0; st < 4; ++st)
            pm[st] = fmaxf(fmaxf(p[st][0], p[st][1]), fmaxf(p[st][2], p[st][3]));
        float pmax = fmaxf(fmaxf(pm[0], pm[1]), fmaxf(pm[2], pm[3]));
        pmax = fmaxf(pmax, __shfl_xor(pmax, 16));
        pmax = fmaxf(pmax, __shfl_xor(pmax, 32));

        if (!__all(pmax <= mval)) {
            const float mnew  = fmaxf(mval, pmax);
            const float alpha = exp2f(mval - mnew);
            mval = mnew;
            lsum *= alpha;
#pragma unroll
            for (int ht = 0; ht < 4; ++ht) oT[ht] *= alpha;
        }

        float ps[4];
#pragma unroll
        for (int st = 0; st < 4; ++st) {
#pragma unroll
            for (int r = 0; r < 4; ++r)
                p[st][r] = exp2f(p[st][r] - mval);
            ps[st] = (p[st][0] + p[st][1]) + (p[st][2] + p[st][3]);
        }
        float srow = (ps[0] + ps[1]) + (ps[2] + ps[3]);
        srow += __shfl_xor(srow, 16);
        srow += __shfl_xor(srow, 32);
        lsum += srow;

        short8 pb[2];
#pragma unroll
        for (int ks = 0; ks < 2; ++ks) {
#pragma unroll
            for (int r = 0; r < 4; ++r) {
                pb[ks][r]     = (short)f2bf(p[2 * ks][r]);
                pb[ks][r + 4] = (short)f2bf(p[2 * ks + 1][r]);
            }
        }

#pragma unroll
        for (int ks = 0; ks < 2; ++ks) {
#pragma unroll
            for (int ht = 0; ht < 4; ++ht) {
                const short8 vf = make_frag(&Vt[swz(ht * 16 + lc, ks * 32 + lg * 4)],
                                            &Vt[swz(ht * 16 + lc, ks * 32 + lg * 4 + 16)]);
                oT[ht] = __builtin_amdgcn_mfma_f32_16x16x32_bf16(vf, pb[ks], oT[ht], 0, 0, 0);
            }
        }
    }

    const float inv = 1.f / lsum;
    float* op = out + (size_t)(b * T_ + q_glob) * H_;
#pragma unroll
    for (int ht = 0; ht < 4; ++ht) {
        f32x4 v = oT[ht] * inv;
        *reinterpret_cast<f32x4*>(&op[ht * 16 + lg * 4]) = v;
    }
}

extern "C" void kernel_launch(void* const* d_in, const int* in_sizes, int n_in,
                              void* d_out, int out_size, void* d_ws, size_t ws_size,
                              hipStream_t stream) {
    const float* x  = (const float*)d_in[0];
    const float* Wk = (const float*)d_in[1];
    const float* Wq = (const float*)d_in[2];
    const float* Wv = (const float*)d_in[3];

    const size_t qkvB = (size_t)3 * M_ * H_ * 2;          // 6,291,456
    const size_t WtB  = (size_t)3 * H_ * C_ * 2;          //   294,912
    unsigned short* qkv = (unsigned short*)d_ws;
    unsigned short* Wt  = (unsigned short*)((char*)d_ws + qkvB);
    float* part = (float*)((char*)d_ws + qkvB + WtB);
    float* out  = (float*)d_out;

    prep_w<<<dim3(144), dim3(256), 0, stream>>>(Wq, Wk, Wv, Wt);
    proj_kernel<<<dim3(M_ / 32), dim3(256), 0, stream>>>(x, Wt, qkv);

    const size_t need8  = qkvB + WtB + (size_t)(B_ * 80) * SEG_FLOATS * 4;
    const size_t need32 = qkvB + WtB + (size_t)(B_ * 32) * SEG_FLOATS * 4;
    if (ws_size >= need8) {
        attn_partial<8><<<dim3(B_ * 80), dim3(256), 0, stream>>>(qkv, part);
        attn_merge<8><<<dim3(B_ * 32), dim3(256), 0, stream>>>(part, out);
    } else if (ws_size >= need32) {
        attn_partial<32><<<dim3(B_ * 32), dim3(256), 0, stream>>>(qkv, part);
        attn_merge<32><<<dim3(B_ * 32), dim3(256), 0, stream>>>(part, out);
    } else {
        attn_kernel<<<dim3(B_ * 32), dim3(256), 0, stream>>>(qkv, out);
    }
}

// Round 6
// 58.376 us; speedup vs baseline: 1.1450x; 1.1450x over previous
//
#include <hip/hip_runtime.h>
#include <hip/hip_bf16.h>

typedef __attribute__((ext_vector_type(8))) short short8;
typedef __attribute__((ext_vector_type(4))) float f32x4;

#define B_  8
#define T_  2048
#define C_  768
#define H_  64
#define M_  (B_ * T_)   // 16384 rows

// direct global -> LDS, 16 B per lane; LDS dest must be wave-uniform base.
#define GLDS16(g, l) __builtin_amdgcn_global_load_lds(                        \
    (const __attribute__((address_space(1))) void*)(g),                       \
    (__attribute__((address_space(3))) void*)(l), 16, 0, 0)

static __device__ __forceinline__ unsigned short f2bf(float f) {
    __hip_bfloat16 h = __float2bfloat16(f);
    return *reinterpret_cast<unsigned short*>(&h);
}

static __device__ __forceinline__ short8 make_frag(const unsigned short* p0, const unsigned short* p1) {
    const ushort4 a = *reinterpret_cast<const ushort4*>(p0);
    const ushort4 b = *reinterpret_cast<const ushort4*>(p1);
    short8 r;
    r[0] = (short)a.x; r[1] = (short)a.y; r[2] = (short)a.z; r[3] = (short)a.w;
    r[4] = (short)b.x; r[5] = (short)b.y; r[6] = (short)b.z; r[7] = (short)b.w;
    return r;
}

// XOR swizzle for 64-ushort (128 B) rows: permute 16 B chunk idx with row&7.
static __device__ __forceinline__ int swz(int row, int u) {
    return row * 64 + ((((u) >> 3) ^ (row & 7)) << 3) + (u & 7);
}

// ---------------------------------------------------------------------------
// Kernel 0: W -> Wt  (transpose + fp32->bf16).  Wt[192][768] bf16.
// ---------------------------------------------------------------------------
__global__ __launch_bounds__(256) void prep_w(
    const float* __restrict__ Wq, const float* __restrict__ Wk, const float* __restrict__ Wv,
    unsigned short* __restrict__ Wt) {

    const int t   = threadIdx.x;
    const int mat = blockIdx.x / 48;
    const int kb  = blockIdx.x % 48;
    const int h   = t & 63;
    const int k0  = (kb * 4 + (t >> 6)) * 4;

    const float* Ws = (mat == 0) ? Wq : (mat == 1) ? Wk : Wv;
    ushort4 o;
    o.x = f2bf(Ws[(size_t)(k0 + 0) * H_ + h]);
    o.y = f2bf(Ws[(size_t)(k0 + 1) * H_ + h]);
    o.z = f2bf(Ws[(size_t)(k0 + 2) * H_ + h]);
    o.w = f2bf(Ws[(size_t)(k0 + 3) * H_ + h]);
    *reinterpret_cast<ushort4*>(&Wt[(size_t)(mat * 64 + h) * C_ + k0]) = o;
}

// ---------------------------------------------------------------------------
// Kernel 1: fused QKV projection (round-4 64-row structure).  Epilogue now
// writes K and V as per-tile pre-swizzled LDS images:
//   Kimg[tile][swz(s&63, h)]   (QK^T operand layout)
//   Vimg[tile][swz(h, s&63)]   (transposed PV operand layout)
// so the attention kernel can stage them with linear global_load_lds.
// ---------------------------------------------------------------------------
__global__ __launch_bounds__(256) void proj_kernel(
    const float* __restrict__ x, const unsigned short* __restrict__ Wt,
    unsigned short* __restrict__ qkv) {

    __shared__ unsigned short Als[4 * 12 * 512];   // 48 KB

    const int tid = threadIdx.x;
    const int w   = tid >> 6;
    const int l   = tid & 63;
    const int lg  = l >> 4;
    const int lc  = l & 15;
    const int row0 = blockIdx.x * 64;

    const int sr   = tid >> 2;
    const int so   = tid & 3;
    const int srt  = sr >> 4;
    const int sr15 = sr & 15;
    const int sbase = (so * 16 + (sr15 ^ so)) * 8;

    f32x4 acc[4][3];
#pragma unroll
    for (int rt = 0; rt < 4; ++rt)
#pragma unroll
        for (int ct = 0; ct < 3; ++ct) acc[rt][ct] = (f32x4)0.f;

    const unsigned short* bbase[3];
#pragma unroll
    for (int ct = 0; ct < 3; ++ct)
        bbase[ct] = Wt + (size_t)(w * 48 + ct * 16 + lc) * C_ + lg * 8;

    for (int phase = 0; phase < 2; ++phase) {
        if (phase) __syncthreads();
#pragma unroll
        for (int g = 0; g < 3; ++g) {
            float4 fa[4][2];
#pragma unroll
            for (int jj = 0; jj < 4; ++jj) {
                const int j = g * 4 + jj;
                const float* xp = x + (size_t)(row0 + sr) * C_ + phase * 384 + j * 32 + so * 8;
                fa[jj][0] = *reinterpret_cast<const float4*>(xp);
                fa[jj][1] = *reinterpret_cast<const float4*>(xp + 4);
            }
#pragma unroll
            for (int jj = 0; jj < 4; ++jj) {
                const int j = g * 4 + jj;
                short8 v;
                v[0] = (short)f2bf(fa[jj][0].x); v[1] = (short)f2bf(fa[jj][0].y);
                v[2] = (short)f2bf(fa[jj][0].z); v[3] = (short)f2bf(fa[jj][0].w);
                v[4] = (short)f2bf(fa[jj][1].x); v[5] = (short)f2bf(fa[jj][1].y);
                v[6] = (short)f2bf(fa[jj][1].z); v[7] = (short)f2bf(fa[jj][1].w);
                *reinterpret_cast<short8*>(&Als[(srt * 12 + j) * 512 + sbase]) = v;
            }
        }
        __syncthreads();

        short8 bcur[3], bnxt[3];
#pragma unroll
        for (int ct = 0; ct < 3; ++ct)
            bcur[ct] = *reinterpret_cast<const short8*>(bbase[ct] + phase * 384);

#pragma unroll
        for (int kk = 0; kk < 12; ++kk) {
            if (kk < 11) {
#pragma unroll
                for (int ct = 0; ct < 3; ++ct)
                    bnxt[ct] = *reinterpret_cast<const short8*>(bbase[ct] + phase * 384 + (kk + 1) * 32);
            }
            short8 af[4];
#pragma unroll
            for (int rt = 0; rt < 4; ++rt)
                af[rt] = *reinterpret_cast<const short8*>(
                    &Als[(rt * 12 + kk) * 512 + (lg * 16 + (lc ^ lg)) * 8]);
#pragma unroll
            for (int rt = 0; rt < 4; ++rt)
#pragma unroll
                for (int ct = 0; ct < 3; ++ct)
                    acc[rt][ct] = __builtin_amdgcn_mfma_f32_16x16x32_bf16(af[rt], bcur[ct], acc[rt][ct], 0, 0, 0);
            if (kk < 11) {
#pragma unroll
                for (int ct = 0; ct < 3; ++ct) bcur[ct] = bnxt[ct];
            }
        }
    }

    // ---- epilogue: Q row-major; K/V as pre-swizzled tile images
    unsigned short* Qd   = qkv;
    unsigned short* Kimg = qkv + (size_t)M_ * H_;
    unsigned short* Vimg = qkv + (size_t)2 * M_ * H_;
#pragma unroll
    for (int ct = 0; ct < 3; ++ct) {
        const int col = w * 48 + ct * 16 + lc;
        const int mat = col >> 6;
        const int h   = col & 63;
#pragma unroll
        for (int rt = 0; rt < 4; ++rt)
#pragma unroll
            for (int j = 0; j < 4; ++j) {
                const int grow = row0 + rt * 16 + lg * 4 + j;
                const unsigned short v = f2bf(acc[rt][ct][j]);
                if (mat == 0) {
                    Qd[(size_t)grow * H_ + h] = v;
                } else {
                    const int g  = grow >> 6;
                    const int s6 = grow & 63;
                    if (mat == 1) Kimg[((size_t)g << 12) + swz(s6, h)] = v;
                    else          Vimg[((size_t)g << 12) + swz(h, s6)] = v;
                }
            }
    }
}

// ---------------------------------------------------------------------------
// Segment bookkeeping for split-KV flash attention (KV tiles of 64 rows).
// ---------------------------------------------------------------------------
#define SEG_FLOATS 4224
#define LOG2E_SCALE 0.18033688011112042f   // 0.125 * log2(e)

template<int SEG>
static __device__ __forceinline__ int segs_per_batch() { return SEG == 32 ? 32 : 80; }

template<int SEG>
static __device__ __forceinline__ void decode_seg(int r, int& qt, int& seg) {
    if (SEG == 32) { qt = r; seg = 0; return; }
    if (r < 8)       { qt = r;                seg = 0; }
    else if (r < 24) { qt = 8  + (r - 8) / 2; seg = (r - 8) & 1; }
    else if (r < 48) { qt = 16 + (r - 24) / 3; seg = (r - 24) % 3; }
    else             { qt = 24 + (r - 48) / 4; seg = (r - 48) & 3; }
}

template<int SEG>
static __device__ __forceinline__ int seg_prefix(int qt) {
    if (SEG == 32) return qt;
    if (qt < 8)  return qt;
    if (qt < 16) return 8  + 2 * (qt - 8);
    if (qt < 24) return 24 + 3 * (qt - 16);
    return 48 + 4 * (qt - 24);
}

// ---------------------------------------------------------------------------
// Kernel 2a: partial causal flash attention.  Swapped-operand MFMA form +
// global_load_lds double-buffered staging from pre-swizzled K/V images:
//   barrier(A: prev compute done) -> stage(next buf, 4 gload_lds) ->
//   vmcnt(4) (own cur loads done) -> barrier(B) -> compute(cur).
// Next tile's loads stay in flight across compute; vmcnt never drains to 0
// mid-loop.
// ---------------------------------------------------------------------------
template<int SEG>
__global__ __launch_bounds__(256) void attn_partial(
    const unsigned short* __restrict__ qkv, float* __restrict__ part) {

    const int spb = segs_per_batch<SEG>();
    const int b   = blockIdx.x / spb;
    const int r_  = blockIdx.x % spb;
    int qt, seg;
    decode_seg<SEG>(r_, qt, seg);

    const int tid = threadIdx.x;
    const int w  = tid >> 6;
    const int l  = tid & 63;
    const int lg = l >> 4;
    const int lc = l & 15;

    __shared__ unsigned short Kls[2][4096];   // pre-swizzled K tile images
    __shared__ unsigned short Vls[2][4096];   // pre-swizzled V^T tile images

    const unsigned short* Qg = qkv;
    const unsigned short* Kg = qkv + (size_t)M_ * H_;
    const unsigned short* Vg = qkv + (size_t)2 * M_ * H_;

    // Q fragment (B-operand: col = q = w*16+lc, k = h)
    const unsigned short* qrow = Qg + (size_t)(b * T_ + qt * 64 + w * 16 + lc) * H_;
    short8 qf[2];
#pragma unroll
    for (int ks = 0; ks < 2; ++ks)
        qf[ks] = make_frag(qrow + ks * 32 + lg * 4, qrow + ks * 32 + lg * 4 + 16);

    float mval = -1e30f, lsum = 0.f;   // per-lane state for q = w*16+lc
    f32x4 oT[4];                       // O^T: h = ht*16+4*lg+reg, q = lc
#pragma unroll
    for (int t = 0; t < 4; ++t) oT[t] = (f32x4)0.f;

    const int q_glob = qt * 64 + w * 16 + lc;

    const int kv_beg = seg * SEG;
    const int kv_end = min(kv_beg + SEG, qt + 1);

    const int go = w * 1024 + l * 8;   // ushort offset this lane copies

    auto stage = [&](int buf, int kv) {
        const size_t tb = ((size_t)(b * 32 + kv)) << 12;   // tile base (ushorts)
        const unsigned short* kt = Kg + tb;
        const unsigned short* vt = Vg + tb;
        GLDS16(kt + go,       &Kls[buf][w * 1024]);
        GLDS16(kt + go + 512, &Kls[buf][w * 1024 + 512]);
        GLDS16(vt + go,       &Vls[buf][w * 1024]);
        GLDS16(vt + go + 512, &Vls[buf][w * 1024 + 512]);
    };

    stage(0, kv_beg);
    int cur = 0;

    for (int kv = kv_beg; kv < kv_end; ++kv) {
        const bool more = (kv + 1 < kv_end);
        __builtin_amdgcn_s_barrier();              // (A) prev compute done
        asm volatile("" ::: "memory");
        if (more) {
            stage(cur ^ 1, kv + 1);
            asm volatile("s_waitcnt vmcnt(4)" ::: "memory");
        } else {
            asm volatile("s_waitcnt vmcnt(0)" ::: "memory");
        }
        __builtin_amdgcn_s_barrier();              // (B) cur tile resident
        asm volatile("" ::: "memory");

        const unsigned short* Kc = Kls[cur];
        const unsigned short* Vc = Vls[cur];

        // ---- S^T = (K Q^T): rows s = st*16 + 4*lg + reg, col q = lc
        f32x4 sT[4];
#pragma unroll
        for (int st = 0; st < 4; ++st) {
            f32x4 accs = (f32x4)0.f;
#pragma unroll
            for (int ks = 0; ks < 2; ++ks) {
                const short8 kf = make_frag(&Kc[swz(st * 16 + lc, ks * 32 + lg * 4)],
                                            &Kc[swz(st * 16 + lc, ks * 32 + lg * 4 + 16)]);
                accs = __builtin_amdgcn_mfma_f32_16x16x32_bf16(kf, qf[ks], accs, 0, 0, 0);
            }
            sT[st] = accs;
        }

        // ---- in-register online softmax (log2 domain)
        float p[4][4];
#pragma unroll
        for (int st = 0; st < 4; ++st)
#pragma unroll
            for (int r = 0; r < 4; ++r)
                p[st][r] = sT[st][r] * LOG2E_SCALE;

        if (kv == qt) {
#pragma unroll
            for (int st = 0; st < 4; ++st)
#pragma unroll
                for (int r = 0; r < 4; ++r)
                    if ((kv * 64 + st * 16 + lg * 4 + r) > q_glob) p[st][r] = -1e30f;
        }

        float pm[4];
#pragma unroll
        for (int st = 0; st < 4; ++st)
            pm[st] = fmaxf(fmaxf(p[st][0], p[st][1]), fmaxf(p[st][2], p[st][3]));
        float pmax = fmaxf(fmaxf(pm[0], pm[1]), fmaxf(pm[2], pm[3]));
        pmax = fmaxf(pmax, __shfl_xor(pmax, 16));
        pmax = fmaxf(pmax, __shfl_xor(pmax, 32));

        if (!__all(pmax <= mval)) {                // exact defer-rescale
            const float mnew  = fmaxf(mval, pmax);
            const float alpha = exp2f(mval - mnew);
            mval = mnew;
            lsum *= alpha;
#pragma unroll
            for (int ht = 0; ht < 4; ++ht) oT[ht] *= alpha;
        }

        float ps[4];
#pragma unroll
        for (int st = 0; st < 4; ++st) {
#pragma unroll
            for (int r = 0; r < 4; ++r)
                p[st][r] = exp2f(p[st][r] - mval);
            ps[st] = (p[st][0] + p[st][1]) + (p[st][2] + p[st][3]);
        }
        float srow = (ps[0] + ps[1]) + (ps[2] + ps[3]);
        srow += __shfl_xor(srow, 16);
        srow += __shfl_xor(srow, 32);
        lsum += srow;

        // ---- pack P^T -> bf16 B-frags (layout identity: D row s == B-frag k)
        short8 pb[2];
#pragma unroll
        for (int ks = 0; ks < 2; ++ks) {
#pragma unroll
            for (int r = 0; r < 4; ++r) {
                pb[ks][r]     = (short)f2bf(p[2 * ks][r]);
                pb[ks][r + 4] = (short)f2bf(p[2 * ks + 1][r]);
            }
        }

        // ---- O^T += V^T P^T
#pragma unroll
        for (int ks = 0; ks < 2; ++ks) {
#pragma unroll
            for (int ht = 0; ht < 4; ++ht) {
                const short8 vf = make_frag(&Vc[swz(ht * 16 + lc, ks * 32 + lg * 4)],
                                            &Vc[swz(ht * 16 + lc, ks * 32 + lg * 4 + 16)]);
                oT[ht] = __builtin_amdgcn_mfma_f32_16x16x32_bf16(vf, pb[ks], oT[ht], 0, 0, 0);
            }
        }
        cur ^= 1;
    }

    // ---- write partial: O^T regs land as [q][h] float4 stores
    float* base = part + (size_t)blockIdx.x * SEG_FLOATS;
#pragma unroll
    for (int ht = 0; ht < 4; ++ht)
        *reinterpret_cast<f32x4*>(&base[(w * 16 + lc) * 64 + ht * 16 + lg * 4]) = oT[ht];
    if (lg == 0) {
        base[4096 + w * 16 + lc] = mval;
        base[4160 + w * 16 + lc] = lsum;
    }
}

// ---------------------------------------------------------------------------
// Kernel 2b: merge segments, normalize, write output.
// ---------------------------------------------------------------------------
template<int SEG>
__global__ __launch_bounds__(256) void attn_merge(
    const float* __restrict__ part, float* __restrict__ out) {

    const int b  = blockIdx.x >> 5;
    const int qt = blockIdx.x & 31;
    const int nseg = (SEG == 32) ? 1 : (qt / 8 + 1);
    const int spb  = segs_per_batch<SEG>();
    const float* base0 = part + (size_t)(b * spb + seg_prefix<SEG>(qt)) * SEG_FLOATS;

    const int tid = threadIdx.x;
    const int row = tid >> 2;
    const int c0  = (tid & 3) * 16;

    float M = -1e30f;
    for (int s = 0; s < nseg; ++s)
        M = fmaxf(M, base0[(size_t)s * SEG_FLOATS + 4096 + row]);

    float L = 0.f;
    f32x4 acc[4];
#pragma unroll
    for (int k = 0; k < 4; ++k) acc[k] = (f32x4)0.f;

    for (int s = 0; s < nseg; ++s) {
        const float* sb = base0 + (size_t)s * SEG_FLOATS;
        const float wsc = exp2f(sb[4096 + row] - M);
        L += sb[4160 + row] * wsc;
#pragma unroll
        for (int k = 0; k < 4; ++k) {
            const f32x4 ov = *reinterpret_cast<const f32x4*>(&sb[row * 64 + c0 + 4 * k]);
            acc[k] += ov * wsc;
        }
    }
    const float inv = 1.f / L;
    float* op = out + (size_t)(b * T_ + qt * 64 + row) * H_ + c0;
#pragma unroll
    for (int k = 0; k < 4; ++k)
        *reinterpret_cast<f32x4*>(&op[4 * k]) = acc[k] * inv;
}

// ---------------------------------------------------------------------------
// Fallback: single-pass attention (only if ws too small for split-KV).
// Staging is a plain linear copy since the images ARE the LDS layout.
// ---------------------------------------------------------------------------
__global__ __launch_bounds__(256) void attn_kernel(
    const unsigned short* __restrict__ qkv, float* __restrict__ out) {

    const int b  = blockIdx.x >> 5;
    const int qt = blockIdx.x & 31;
    const int tid = threadIdx.x;
    const int w  = tid >> 6;
    const int l  = tid & 63;
    const int lg = l >> 4;
    const int lc = l & 15;

    __shared__ unsigned short Kl[4096];
    __shared__ unsigned short Vt[4096];

    const unsigned short* Qg = qkv;
    const unsigned short* Kg = qkv + (size_t)M_ * H_;
    const unsigned short* Vg = qkv + (size_t)2 * M_ * H_;

    const unsigned short* qrow = Qg + (size_t)(b * T_ + qt * 64 + w * 16 + lc) * H_;
    short8 qf[2];
#pragma unroll
    for (int ks = 0; ks < 2; ++ks)
        qf[ks] = make_frag(qrow + ks * 32 + lg * 4, qrow + ks * 32 + lg * 4 + 16);

    float mval = -1e30f, lsum = 0.f;
    f32x4 oT[4];
#pragma unroll
    for (int t = 0; t < 4; ++t) oT[t] = (f32x4)0.f;

    const int q_glob = qt * 64 + w * 16 + lc;

    for (int kv = 0; kv <= qt; ++kv) {
        __syncthreads();
        const size_t tb = ((size_t)(b * 32 + kv)) << 12;
        reinterpret_cast<short8*>(Kl)[tid]       = reinterpret_cast<const short8*>(Kg + tb)[tid];
        reinterpret_cast<short8*>(Kl)[tid + 256] = reinterpret_cast<const short8*>(Kg + tb)[tid + 256];
        reinterpret_cast<short8*>(Vt)[tid]       = reinterpret_cast<const short8*>(Vg + tb)[tid];
        reinterpret_cast<short8*>(Vt)[tid + 256] = reinterpret_cast<const short8*>(Vg + tb)[tid + 256];
        __syncthreads();

        f32x4 sT[4];
#pragma unroll
        for (int st = 0; st < 4; ++st) {
            f32x4 accs = (f32x4)0.f;
#pragma unroll
            for (int ks = 0; ks < 2; ++ks) {
                const short8 kf = make_frag(&Kl[swz(st * 16 + lc, ks * 32 + lg * 4)],
                                            &Kl[swz(st * 16 + lc, ks * 32 + lg * 4 + 16)]);
                accs = __builtin_amdgcn_mfma_f32_16x16x32_bf16(kf, qf[ks], accs, 0, 0, 0);
            }
            sT[st] = accs;
        }

        float p[4][4];
#pragma unroll
        for (int st = 0; st < 4; ++st)
#pragma unroll
            for (int r = 0; r < 4; ++r)
                p[st][r] = sT[st][r] * LOG2E_SCALE;

        if (kv == qt) {
#pragma unroll
            for (int st = 0; st < 4; ++st)
#pragma unroll
                for (int r = 0; r < 4; ++r)
                    if ((kv * 64 + st * 16 + lg * 4 + r) > q_glob) p[st][r] = -1e30f;
        }

        float pm[4];
#pragma unroll
        for (int st = 0; st < 4; ++st)
            pm[st] = fmaxf(fmaxf(p[st][0], p[st][1]), fmaxf(p[st][2], p[st][3]));
        float pmax = fmaxf(fmaxf(pm[0], pm[1]), fmaxf(pm[2], pm[3]));
        pmax = fmaxf(pmax, __shfl_xor(pmax, 16));
        pmax = fmaxf(pmax, __shfl_xor(pmax, 32));

        if (!__all(pmax <= mval)) {
            const float mnew  = fmaxf(mval, pmax);
            const float alpha = exp2f(mval - mnew);
            mval = mnew;
            lsum *= alpha;
#pragma unroll
            for (int ht = 0; ht < 4; ++ht) oT[ht] *= alpha;
        }

        float ps[4];
#pragma unroll
        for (int st = 0; st < 4; ++st) {
#pragma unroll
            for (int r = 0; r < 4; ++r)
                p[st][r] = exp2f(p[st][r] - mval);
            ps[st] = (p[st][0] + p[st][1]) + (p[st][2] + p[st][3]);
        }
        float srow = (ps[0] + ps[1]) + (ps[2] + ps[3]);
        srow += __shfl_xor(srow, 16);
        srow += __shfl_xor(srow, 32);
        lsum += srow;

        short8 pb[2];
#pragma unroll
        for (int ks = 0; ks < 2; ++ks) {
#pragma unroll
            for (int r = 0; r < 4; ++r) {
                pb[ks][r]     = (short)f2bf(p[2 * ks][r]);
                pb[ks][r + 4] = (short)f2bf(p[2 * ks + 1][r]);
            }
        }

#pragma unroll
        for (int ks = 0; ks < 2; ++ks) {
#pragma unroll
            for (int ht = 0; ht < 4; ++ht) {
                const short8 vf = make_frag(&Vt[swz(ht * 16 + lc, ks * 32 + lg * 4)],
                                            &Vt[swz(ht * 16 + lc, ks * 32 + lg * 4 + 16)]);
                oT[ht] = __builtin_amdgcn_mfma_f32_16x16x32_bf16(vf, pb[ks], oT[ht], 0, 0, 0);
            }
        }
    }

    const float inv = 1.f / lsum;
    float* op = out + (size_t)(b * T_ + q_glob) * H_;
#pragma unroll
    for (int ht = 0; ht < 4; ++ht) {
        f32x4 v = oT[ht] * inv;
        *reinterpret_cast<f32x4*>(&op[ht * 16 + lg * 4]) = v;
    }
}

extern "C" void kernel_launch(void* const* d_in, const int* in_sizes, int n_in,
                              void* d_out, int out_size, void* d_ws, size_t ws_size,
                              hipStream_t stream) {
    const float* x  = (const float*)d_in[0];
    const float* Wk = (const float*)d_in[1];
    const float* Wq = (const float*)d_in[2];
    const float* Wv = (const float*)d_in[3];

    const size_t qkvB = (size_t)3 * M_ * H_ * 2;          // 6,291,456
    const size_t WtB  = (size_t)3 * H_ * C_ * 2;          //   294,912
    unsigned short* qkv = (unsigned short*)d_ws;
    unsigned short* Wt  = (unsigned short*)((char*)d_ws + qkvB);
    float* part = (float*)((char*)d_ws + qkvB + WtB);
    float* out  = (float*)d_out;

    prep_w<<<dim3(144), dim3(256), 0, stream>>>(Wq, Wk, Wv, Wt);
    proj_kernel<<<dim3(M_ / 64), dim3(256), 0, stream>>>(x, Wt, qkv);

    const size_t need8  = qkvB + WtB + (size_t)(B_ * 80) * SEG_FLOATS * 4;
    const size_t need32 = qkvB + WtB + (size_t)(B_ * 32) * SEG_FLOATS * 4;
    if (ws_size >= need8) {
        attn_partial<8><<<dim3(B_ * 80), dim3(256), 0, stream>>>(qkv, part);
        attn_merge<8><<<dim3(B_ * 32), dim3(256), 0, stream>>>(part, out);
    } else if (ws_size >= need32) {
        attn_partial<32><<<dim3(B_ * 32), dim3(256), 0, stream>>>(qkv, part);
        attn_merge<32><<<dim3(B_ * 32), dim3(256), 0, stream>>>(part, out);
    } else {
        attn_kernel<<<dim3(B_ * 32), dim3(256), 0, stream>>>(qkv, out);
    }
}

// Round 7
// 55.769 us; speedup vs baseline: 1.1985x; 1.0467x over previous
//
#include <hip/hip_runtime.h>
#include <hip/hip_bf16.h>

typedef __attribute__((ext_vector_type(8))) short short8;
typedef __attribute__((ext_vector_type(4))) float f32x4;

#define B_  8
#define T_  2048
#define C_  768
#define H_  64
#define M_  (B_ * T_)   // 16384 rows

// direct global -> LDS, 16 B per lane; LDS dest must be wave-uniform base.
#define GLDS16(g, l) __builtin_amdgcn_global_load_lds(                        \
    (const __attribute__((address_space(1))) void*)(g),                       \
    (__attribute__((address_space(3))) void*)(l), 16, 0, 0)

static __device__ __forceinline__ unsigned short f2bf(float f) {
    __hip_bfloat16 h = __float2bfloat16(f);
    return *reinterpret_cast<unsigned short*>(&h);
}

static __device__ __forceinline__ short8 make_frag(const unsigned short* p0, const unsigned short* p1) {
    const ushort4 a = *reinterpret_cast<const ushort4*>(p0);
    const ushort4 b = *reinterpret_cast<const ushort4*>(p1);
    short8 r;
    r[0] = (short)a.x; r[1] = (short)a.y; r[2] = (short)a.z; r[3] = (short)a.w;
    r[4] = (short)b.x; r[5] = (short)b.y; r[6] = (short)b.z; r[7] = (short)b.w;
    return r;
}

// XOR swizzle for 64-ushort (128 B) rows: permute 16 B chunk idx with row&7.
static __device__ __forceinline__ int swz(int row, int u) {
    return row * 64 + ((((u) >> 3) ^ (row & 7)) << 3) + (u & 7);
}

// Fragment-order position of element k (0..63) within a 64-elem image row:
// chunk c = (k>>5)*4 + ((k>>2)&3) holds {32h+4o..+3, 32h+16+4o..+3} so a
// lane's MFMA fragment (k = 32ks+4lg+j / +16) is one contiguous 16 B chunk.
static __device__ __forceinline__ int fragoff(int k) {
    const int half = k >> 5;
    const int kk   = k & 31;
    const int c    = half * 4 + ((kk >> 2) & 3);
    const int p    = (kk & 3) + ((kk & 16) >> 2);
    return c * 8 + p;
}

#define LOG2E_SCALE 0.18033688011112042f   // 0.125 * log2(e), folded into Wq

// ---------------------------------------------------------------------------
// Kernel 0: W -> Wt (transpose + fp32->bf16).  Wq pre-scaled by 0.125*log2e
// so S^T = K·Q^T emerges already in the log2 softmax domain.
// ---------------------------------------------------------------------------
__global__ __launch_bounds__(256) void prep_w(
    const float* __restrict__ Wq, const float* __restrict__ Wk, const float* __restrict__ Wv,
    unsigned short* __restrict__ Wt) {

    const int t   = threadIdx.x;
    const int mat = blockIdx.x / 48;
    const int kb  = blockIdx.x % 48;
    const int h   = t & 63;
    const int k0  = (kb * 4 + (t >> 6)) * 4;

    const float* Ws = (mat == 0) ? Wq : (mat == 1) ? Wk : Wv;
    const float sc  = (mat == 0) ? LOG2E_SCALE : 1.f;
    ushort4 o;
    o.x = f2bf(Ws[(size_t)(k0 + 0) * H_ + h] * sc);
    o.y = f2bf(Ws[(size_t)(k0 + 1) * H_ + h] * sc);
    o.z = f2bf(Ws[(size_t)(k0 + 2) * H_ + h] * sc);
    o.w = f2bf(Ws[(size_t)(k0 + 3) * H_ + h] * sc);
    *reinterpret_cast<ushort4*>(&Wt[(size_t)(mat * 64 + h) * C_ + k0]) = o;
}

// ---------------------------------------------------------------------------
// Kernel 1: fused QKV projection.  Epilogue writes K/V as per-tile
// fragment-ordered + XOR-swizzled LDS images:
//   Kimg[tile][swz(s, fragoff(h))], Vimg[tile][swz(h, fragoff(s))]
// so attention frag reads are single contiguous ds_read_b128.
// ---------------------------------------------------------------------------
__global__ __launch_bounds__(256) void proj_kernel(
    const float* __restrict__ x, const unsigned short* __restrict__ Wt,
    unsigned short* __restrict__ qkv) {

    __shared__ unsigned short Als[4 * 12 * 512];   // 48 KB

    const int tid = threadIdx.x;
    const int w   = tid >> 6;
    const int l   = tid & 63;
    const int lg  = l >> 4;
    const int lc  = l & 15;
    const int row0 = blockIdx.x * 64;

    const int sr   = tid >> 2;
    const int so   = tid & 3;
    const int srt  = sr >> 4;
    const int sr15 = sr & 15;
    const int sbase = (so * 16 + (sr15 ^ so)) * 8;

    f32x4 acc[4][3];
#pragma unroll
    for (int rt = 0; rt < 4; ++rt)
#pragma unroll
        for (int ct = 0; ct < 3; ++ct) acc[rt][ct] = (f32x4)0.f;

    const unsigned short* bbase[3];
#pragma unroll
    for (int ct = 0; ct < 3; ++ct)
        bbase[ct] = Wt + (size_t)(w * 48 + ct * 16 + lc) * C_ + lg * 8;

    for (int phase = 0; phase < 2; ++phase) {
        if (phase) __syncthreads();
#pragma unroll
        for (int g = 0; g < 3; ++g) {
            float4 fa[4][2];
#pragma unroll
            for (int jj = 0; jj < 4; ++jj) {
                const int j = g * 4 + jj;
                const float* xp = x + (size_t)(row0 + sr) * C_ + phase * 384 + j * 32 + so * 8;
                fa[jj][0] = *reinterpret_cast<const float4*>(xp);
                fa[jj][1] = *reinterpret_cast<const float4*>(xp + 4);
            }
#pragma unroll
            for (int jj = 0; jj < 4; ++jj) {
                const int j = g * 4 + jj;
                short8 v;
                v[0] = (short)f2bf(fa[jj][0].x); v[1] = (short)f2bf(fa[jj][0].y);
                v[2] = (short)f2bf(fa[jj][0].z); v[3] = (short)f2bf(fa[jj][0].w);
                v[4] = (short)f2bf(fa[jj][1].x); v[5] = (short)f2bf(fa[jj][1].y);
                v[6] = (short)f2bf(fa[jj][1].z); v[7] = (short)f2bf(fa[jj][1].w);
                *reinterpret_cast<short8*>(&Als[(srt * 12 + j) * 512 + sbase]) = v;
            }
        }
        __syncthreads();

        short8 bcur[3], bnxt[3];
#pragma unroll
        for (int ct = 0; ct < 3; ++ct)
            bcur[ct] = *reinterpret_cast<const short8*>(bbase[ct] + phase * 384);

#pragma unroll
        for (int kk = 0; kk < 12; ++kk) {
            if (kk < 11) {
#pragma unroll
                for (int ct = 0; ct < 3; ++ct)
                    bnxt[ct] = *reinterpret_cast<const short8*>(bbase[ct] + phase * 384 + (kk + 1) * 32);
            }
            short8 af[4];
#pragma unroll
            for (int rt = 0; rt < 4; ++rt)
                af[rt] = *reinterpret_cast<const short8*>(
                    &Als[(rt * 12 + kk) * 512 + (lg * 16 + (lc ^ lg)) * 8]);
#pragma unroll
            for (int rt = 0; rt < 4; ++rt)
#pragma unroll
                for (int ct = 0; ct < 3; ++ct)
                    acc[rt][ct] = __builtin_amdgcn_mfma_f32_16x16x32_bf16(af[rt], bcur[ct], acc[rt][ct], 0, 0, 0);
            if (kk < 11) {
#pragma unroll
                for (int ct = 0; ct < 3; ++ct) bcur[ct] = bnxt[ct];
            }
        }
    }

    // ---- epilogue: Q row-major; K/V as fragment-ordered swizzled images
    unsigned short* Qd   = qkv;
    unsigned short* Kimg = qkv + (size_t)M_ * H_;
    unsigned short* Vimg = qkv + (size_t)2 * M_ * H_;
    const size_t g12 = (size_t)blockIdx.x << 12;   // tile base (row0/64 * 4096)
#pragma unroll
    for (int ct = 0; ct < 3; ++ct) {
        const int col = w * 48 + ct * 16 + lc;
        const int mat = col >> 6;
        const int h   = col & 63;
        const int foh = fragoff(h);
#pragma unroll
        for (int rt = 0; rt < 4; ++rt)
#pragma unroll
            for (int j = 0; j < 4; ++j) {
                const int s6 = rt * 16 + lg * 4 + j;   // row within tile
                const unsigned short v = f2bf(acc[rt][ct][j]);
                if (mat == 0)      Qd[(size_t)(row0 + s6) * H_ + h] = v;
                else if (mat == 1) Kimg[g12 + swz(s6, foh)] = v;
                else               Vimg[g12 + swz(h, fragoff(s6))] = v;
            }
    }
}

// ---------------------------------------------------------------------------
// Segment bookkeeping for split-KV flash attention (KV tiles of 64 rows).
// ---------------------------------------------------------------------------
#define SEG_FLOATS 4224

template<int SEG>
static __device__ __forceinline__ int segs_per_batch() { return SEG == 32 ? 32 : 80; }

template<int SEG>
static __device__ __forceinline__ void decode_seg(int r, int& qt, int& seg) {
    if (SEG == 32) { qt = r; seg = 0; return; }
    if (r < 8)       { qt = r;                seg = 0; }
    else if (r < 24) { qt = 8  + (r - 8) / 2; seg = (r - 8) & 1; }
    else if (r < 48) { qt = 16 + (r - 24) / 3; seg = (r - 24) % 3; }
    else             { qt = 24 + (r - 48) / 4; seg = (r - 48) & 3; }
}

template<int SEG>
static __device__ __forceinline__ int seg_prefix(int qt) {
    if (SEG == 32) return qt;
    if (qt < 8)  return qt;
    if (qt < 16) return 8  + 2 * (qt - 8);
    if (qt < 24) return 24 + 3 * (qt - 16);
    return 48 + 4 * (qt - 24);
}

// ---------------------------------------------------------------------------
// Kernel 2a: partial causal flash attention.  Swapped-operand MFMA; frag
// reads are single ds_read_b128 from fragment-ordered images; gload_lds
// double-buffer with counted vmcnt.  Blocks launched longest-first; q-tiles
// with a single segment write normalized output directly (skip merge).
// ---------------------------------------------------------------------------
template<int SEG>
__global__ __launch_bounds__(256) void attn_partial(
    const unsigned short* __restrict__ qkv, float* __restrict__ part,
    float* __restrict__ out) {

    const int spb = segs_per_batch<SEG>();
    const int b   = blockIdx.x / spb;
    const int rr  = spb - 1 - (blockIdx.x % spb);   // longest blocks first
    int qt, seg;
    decode_seg<SEG>(rr, qt, seg);

    const int tid = threadIdx.x;
    const int w  = tid >> 6;
    const int l  = tid & 63;
    const int lg = l >> 4;
    const int lc = l & 15;

    __shared__ unsigned short Kls[2][4096];   // fragment-ordered K images
    __shared__ unsigned short Vls[2][4096];   // fragment-ordered V^T images

    const unsigned short* Qg = qkv;
    const unsigned short* Kg = qkv + (size_t)M_ * H_;
    const unsigned short* Vg = qkv + (size_t)2 * M_ * H_;

    // Q fragment (B-operand: col = q = w*16+lc, k = h)
    const unsigned short* qrow = Qg + (size_t)(b * T_ + qt * 64 + w * 16 + lc) * H_;
    short8 qf[2];
#pragma unroll
    for (int ks = 0; ks < 2; ++ks)
        qf[ks] = make_frag(qrow + ks * 32 + lg * 4, qrow + ks * 32 + lg * 4 + 16);

    float mval = -1e30f, lsum = 0.f;   // per-lane state for q = w*16+lc
    f32x4 oT[4];                       // O^T: h = ht*16+4*lg+reg, q = lc
#pragma unroll
    for (int t = 0; t < 4; ++t) oT[t] = (f32x4)0.f;

    const int q_glob = qt * 64 + w * 16 + lc;

    const int kv_beg = seg * SEG;
    const int kv_end = min(kv_beg + SEG, qt + 1);

    const int go = w * 1024 + l * 8;   // ushort offset this lane copies

    auto stage = [&](int buf, int kv) {
        const size_t tb = ((size_t)(b * 32 + kv)) << 12;
        const unsigned short* kt = Kg + tb;
        const unsigned short* vt = Vg + tb;
        GLDS16(kt + go,       &Kls[buf][w * 1024]);
        GLDS16(kt + go + 512, &Kls[buf][w * 1024 + 512]);
        GLDS16(vt + go,       &Vls[buf][w * 1024]);
        GLDS16(vt + go + 512, &Vls[buf][w * 1024 + 512]);
    };

    stage(0, kv_beg);
    int cur = 0;

    for (int kv = kv_beg; kv < kv_end; ++kv) {
        const bool more = (kv + 1 < kv_end);
        __builtin_amdgcn_s_barrier();              // (A) prev compute done
        asm volatile("" ::: "memory");
        if (more) {
            stage(cur ^ 1, kv + 1);
            asm volatile("s_waitcnt vmcnt(4)" ::: "memory");
        } else {
            asm volatile("s_waitcnt vmcnt(0)" ::: "memory");
        }
        __builtin_amdgcn_s_barrier();              // (B) cur tile resident
        asm volatile("" ::: "memory");

        const unsigned short* Kc = Kls[cur];
        const unsigned short* Vc = Vls[cur];

        // ---- S^T = (K Q^T), already in log2 domain (scale folded into Wq)
        f32x4 sT[4];
#pragma unroll
        for (int st = 0; st < 4; ++st) {
            f32x4 accs = (f32x4)0.f;
#pragma unroll
            for (int ks = 0; ks < 2; ++ks) {
                const short8 kf = *reinterpret_cast<const short8*>(
                    &Kc[swz(st * 16 + lc, (ks * 4 + lg) * 8)]);
                accs = __builtin_amdgcn_mfma_f32_16x16x32_bf16(kf, qf[ks], accs, 0, 0, 0);
            }
            sT[st] = accs;
        }

        float p[4][4];
#pragma unroll
        for (int st = 0; st < 4; ++st)
#pragma unroll
            for (int r = 0; r < 4; ++r)
                p[st][r] = sT[st][r];

        if (kv == qt) {
#pragma unroll
            for (int st = 0; st < 4; ++st)
#pragma unroll
                for (int r = 0; r < 4; ++r)
                    if ((kv * 64 + st * 16 + lg * 4 + r) > q_glob) p[st][r] = -1e30f;
        }

        float pm[4];
#pragma unroll
        for (int st = 0; st < 4; ++st)
            pm[st] = fmaxf(fmaxf(p[st][0], p[st][1]), fmaxf(p[st][2], p[st][3]));
        float pmax = fmaxf(fmaxf(pm[0], pm[1]), fmaxf(pm[2], pm[3]));
        pmax = fmaxf(pmax, __shfl_xor(pmax, 16));
        pmax = fmaxf(pmax, __shfl_xor(pmax, 32));

        if (!__all(pmax <= mval)) {                // exact defer-rescale
            const float mnew  = fmaxf(mval, pmax);
            const float alpha = exp2f(mval - mnew);
            mval = mnew;
            lsum *= alpha;
#pragma unroll
            for (int ht = 0; ht < 4; ++ht) oT[ht] *= alpha;
        }

        float ps[4];
#pragma unroll
        for (int st = 0; st < 4; ++st) {
#pragma unroll
            for (int r = 0; r < 4; ++r)
                p[st][r] = exp2f(p[st][r] - mval);
            ps[st] = (p[st][0] + p[st][1]) + (p[st][2] + p[st][3]);
        }
        float srow = (ps[0] + ps[1]) + (ps[2] + ps[3]);
        srow += __shfl_xor(srow, 16);
        srow += __shfl_xor(srow, 32);
        lsum += srow;

        // ---- pack P^T -> bf16 B-frags (layout identity: D row s == B-frag k)
        short8 pb[2];
#pragma unroll
        for (int ks = 0; ks < 2; ++ks) {
#pragma unroll
            for (int r = 0; r < 4; ++r) {
                pb[ks][r]     = (short)f2bf(p[2 * ks][r]);
                pb[ks][r + 4] = (short)f2bf(p[2 * ks + 1][r]);
            }
        }

        // ---- O^T += V^T P^T
#pragma unroll
        for (int ks = 0; ks < 2; ++ks) {
#pragma unroll
            for (int ht = 0; ht < 4; ++ht) {
                const short8 vf = *reinterpret_cast<const short8*>(
                    &Vc[swz(ht * 16 + lc, (ks * 4 + lg) * 8)]);
                oT[ht] = __builtin_amdgcn_mfma_f32_16x16x32_bf16(vf, pb[ks], oT[ht], 0, 0, 0);
            }
        }
        cur ^= 1;
    }

    const int nseg = (SEG == 32) ? 1 : (qt / 8 + 1);
    if (nseg == 1) {
        // single segment: write normalized output directly
        const float inv = 1.f / lsum;
        float* op = out + (size_t)(b * T_ + q_glob) * H_;
#pragma unroll
        for (int ht = 0; ht < 4; ++ht) {
            f32x4 v = oT[ht] * inv;
            *reinterpret_cast<f32x4*>(&op[ht * 16 + lg * 4]) = v;
        }
    } else {
        float* base = part + (size_t)(b * spb + seg_prefix<SEG>(qt) + seg) * SEG_FLOATS;
#pragma unroll
        for (int ht = 0; ht < 4; ++ht)
            *reinterpret_cast<f32x4*>(&base[(w * 16 + lc) * 64 + ht * 16 + lg * 4]) = oT[ht];
        if (lg == 0) {
            base[4096 + w * 16 + lc] = mval;
            base[4160 + w * 16 + lc] = lsum;
        }
    }
}

// ---------------------------------------------------------------------------
// Kernel 2b: merge multi-segment q-tiles (qt >= 8), SEG=8 only.
// Grid = B_ * 24 blocks.
// ---------------------------------------------------------------------------
__global__ __launch_bounds__(256) void attn_merge8(
    const float* __restrict__ part, float* __restrict__ out) {

    const int b  = blockIdx.x / 24;
    const int qt = 8 + blockIdx.x % 24;
    const int nseg = qt / 8 + 1;
    const float* base0 = part + (size_t)(b * 80 + seg_prefix<8>(qt)) * SEG_FLOATS;

    const int tid = threadIdx.x;
    const int row = tid >> 2;
    const int c0  = (tid & 3) * 16;

    float M = -1e30f;
    for (int s = 0; s < nseg; ++s)
        M = fmaxf(M, base0[(size_t)s * SEG_FLOATS + 4096 + row]);

    float L = 0.f;
    f32x4 acc[4];
#pragma unroll
    for (int k = 0; k < 4; ++k) acc[k] = (f32x4)0.f;

    for (int s = 0; s < nseg; ++s) {
        const float* sb = base0 + (size_t)s * SEG_FLOATS;
        const float wsc = exp2f(sb[4096 + row] - M);
        L += sb[4160 + row] * wsc;
#pragma unroll
        for (int k = 0; k < 4; ++k) {
            const f32x4 ov = *reinterpret_cast<const f32x4*>(&sb[row * 64 + c0 + 4 * k]);
            acc[k] += ov * wsc;
        }
    }
    const float inv = 1.f / L;
    float* op = out + (size_t)(b * T_ + qt * 64 + row) * H_ + c0;
#pragma unroll
    for (int k = 0; k < 4; ++k)
        *reinterpret_cast<f32x4*>(&op[4 * k]) = acc[k] * inv;
}

extern "C" void kernel_launch(void* const* d_in, const int* in_sizes, int n_in,
                              void* d_out, int out_size, void* d_ws, size_t ws_size,
                              hipStream_t stream) {
    const float* x  = (const float*)d_in[0];
    const float* Wk = (const float*)d_in[1];
    const float* Wq = (const float*)d_in[2];
    const float* Wv = (const float*)d_in[3];

    const size_t qkvB = (size_t)3 * M_ * H_ * 2;          // 6,291,456
    const size_t WtB  = (size_t)3 * H_ * C_ * 2;          //   294,912
    unsigned short* qkv = (unsigned short*)d_ws;
    unsigned short* Wt  = (unsigned short*)((char*)d_ws + qkvB);
    float* part = (float*)((char*)d_ws + qkvB + WtB);
    float* out  = (float*)d_out;

    prep_w<<<dim3(144), dim3(256), 0, stream>>>(Wq, Wk, Wv, Wt);
    proj_kernel<<<dim3(M_ / 64), dim3(256), 0, stream>>>(x, Wt, qkv);

    const size_t need8 = qkvB + WtB + (size_t)(B_ * 80) * SEG_FLOATS * 4;
    if (ws_size >= need8) {
        attn_partial<8><<<dim3(B_ * 80), dim3(256), 0, stream>>>(qkv, part, out);
        attn_merge8<<<dim3(B_ * 24), dim3(256), 0, stream>>>(part, out);
    } else {
        // SEG=32: every q-tile is a single segment -> direct write, no merge
        attn_partial<32><<<dim3(B_ * 32), dim3(256), 0, stream>>>(qkv, part, out);
    }
}